// Round 10
// baseline (268.637 us; speedup 1.0000x reference)
//
#include <hip/hip_runtime.h>

// ---- problem constants (from reference) ----
#define N_NODES   100000
#define T_TYPES   4
#define E_EDGES   400000
#define E4        100000                    // int4 groups per type-array
#define G_TOT     400000                    // total int4 groups = TE_TOT/4
#define TE_TOT    1600000
#define C_CH      2
#define L_LAYERS  2
#define W_INF     128
#define DD        64
#define NUM_CLASS 16
#define BETA      0.5f
#define M_TGT     10000

// CSR build tiling
#define NBKT      782                       // ceil(100000/128) buckets of 128 rows
#define BROWS     128
#define BPAD      2560                      // slots/bucket (mean 2046, sd 45 -> +11 sigma)
#define CHUNK_G   512                       // int4 groups per partition block (2048 edges)
#define NPART_BLK 782                       // ceil(400000/512)

// bf16 planes: u32 at [n*64 + d] = bf16(ch0) | bf16(ch1)<<16
static const size_t PLANE2 = (size_t)N_NODES * DD;    // u32 elements per plane

typedef __attribute__((ext_vector_type(8))) short short8x;   // 8 bf16 (4 VGPRs)
typedef __attribute__((ext_vector_type(4))) float f32x4;     // MFMA C/D

__device__ __forceinline__ unsigned bf16rne(float x) {   // RNE f32 -> bf16 bits
    unsigned u = __float_as_uint(x);
    return (u + 0x7FFFu + ((u >> 16) & 1u)) >> 16;
}
__device__ __forceinline__ unsigned packbf(float a, float b) {
    return bf16rne(a) | (bf16rne(b) << 16);
}
__device__ __forceinline__ float bflo(unsigned u) { return __uint_as_float(u << 16); }
__device__ __forceinline__ float bfhi(unsigned u) { return __uint_as_float(u & 0xFFFF0000u); }

__device__ __forceinline__ void load_filter(const float* cw, int layer,
                                            float* f0, float* f1) {
    float m0 = -1e30f, m1 = -1e30f;
    #pragma unroll
    for (int t = 0; t < T_TYPES; ++t) {
        f0[t] = cw[layer * C_CH * T_TYPES + t];
        f1[t] = cw[layer * C_CH * T_TYPES + T_TYPES + t];
        m0 = fmaxf(m0, f0[t]); m1 = fmaxf(m1, f1[t]);
    }
    float s0 = 0.f, s1 = 0.f;
    #pragma unroll
    for (int t = 0; t < T_TYPES; ++t) {
        f0[t] = __expf(f0[t] - m0); s0 += f0[t];
        f1[t] = __expf(f1[t] - m1); s1 += f1[t];
    }
    #pragma unroll
    for (int t = 0; t < T_TYPES; ++t) { f0[t] /= s0; f1[t] /= s1; }
}

// ---------------------------------------------------------------------------
// prep: Wsb[c][d][k] = bf16(Ws[c][k][d]) (blocks 0..63) + cursor init (64..67)
// ---------------------------------------------------------------------------
__global__ void prep_kernel(const float* __restrict__ Ws,
                            unsigned short* __restrict__ Wsb,
                            int* __restrict__ cursor) {
    int b = blockIdx.x;
    int tid = threadIdx.x;
    if (b < 64) {
        int idx = b * 256 + tid;
        int c   = idx >> 13;
        int rem = idx & 8191;
        int d   = rem >> 7;
        int k   = rem & 127;
        Wsb[idx] = (unsigned short)bf16rne(Ws[c * (W_INF * DD) + k * DD + d]);
    } else {
        int idx = (b - 64) * 256 + tid;
        if (idx < NBKT) cursor[idx] = idx * BPAD;
    }
}

// ---------------------------------------------------------------------------
// Partition edges into bucket-padded 8B records (2048 edges/block, 782 blocks):
//   edata2[pos] = { col | t<<17 | (row&127)<<19 ,
//                   packbf(val*f0_l1[t], val*f1_l1[t]) }
// ---------------------------------------------------------------------------
__global__ __launch_bounds__(256) void partition_kernel(const int* __restrict__ edge_index,
                                                        const float* __restrict__ edge_value,
                                                        const float* __restrict__ cw,
                                                        int* __restrict__ cursor,
                                                        int2* __restrict__ edata2) {
    __shared__ int cnt[NBKT];
    __shared__ int lbase[NBKT];
    __shared__ int gbase[NBKT];
    __shared__ int2 le[CHUNK_G * 4];              // 16 KB
    __shared__ unsigned short lbk[CHUNK_G * 4];   // 4 KB
    int tid = threadIdx.x;
    for (int j = tid; j < NBKT; j += 256) cnt[j] = 0;
    __syncthreads();

    float f0[T_TYPES], f1[T_TYPES];
    load_filter(cw, 0, f0, f1);

    int px[8], pv[8], rk[8], bk[8];
    int ne = 0;
    #pragma unroll
    for (int g = 0; g < 2; ++g) {
        int idx = blockIdx.x * CHUNK_G + g * 256 + tid;
        if (idx < G_TOT) {
            int t = idx / E4, r = idx - t * E4;
            const int* bptr = edge_index + (size_t)t * 2 * E_EDGES;
            int4   rw = ((const int4*)bptr)[r];
            int4   cl = ((const int4*)(bptr + E_EDGES))[r];
            float4 vv = ((const float4*)(edge_value + (size_t)t * E_EDGES))[r];
            int tb = t << 17;
            int   rr[4] = {rw.x, rw.y, rw.z, rw.w};
            int   cc[4] = {cl.x, cl.y, cl.z, cl.w};
            float vf[4] = {vv.x, vv.y, vv.z, vv.w};
            #pragma unroll
            for (int k = 0; k < 4; ++k) {
                int b = rr[k] >> 7;
                px[ne] = cc[k] | tb | ((rr[k] & 127) << 19);
                pv[ne] = __float_as_int(vf[k]);
                bk[ne] = b;
                rk[ne] = atomicAdd(&cnt[b], 1);
                ++ne;
            }
        }
    }
    __syncthreads();
    if (tid < 64) {                                // scan 782 counts, 13/lane
        int c[13]; int s = 0;
        #pragma unroll
        for (int k = 0; k < 13; ++k) {
            int idx = tid * 13 + k;
            c[k] = (idx < NBKT) ? cnt[idx] : 0;
            s += c[k];
        }
        int inc = s;
        #pragma unroll
        for (int off = 1; off < 64; off <<= 1) {
            int v = __shfl_up(inc, off);
            if (tid >= off) inc += v;
        }
        int base = inc - s;
        #pragma unroll
        for (int k = 0; k < 13; ++k) {
            int idx = tid * 13 + k;
            if (idx < NBKT) lbase[idx] = base;
            base += c[k];
        }
    }
    __syncthreads();
    #pragma unroll
    for (int k = 0; k < 8; ++k) {
        if (k < ne) {
            int slot = lbase[bk[k]] + rk[k];
            le[slot]  = make_int2(px[k], pv[k]);
            lbk[slot] = (unsigned short)bk[k];
        }
    }
    __syncthreads();
    for (int j = tid; j < NBKT; j += 256) {
        int c = cnt[j];
        gbase[j] = c ? atomicAdd(&cursor[j], c) : 0;
    }
    __syncthreads();
    int ngrp = min(CHUNK_G, G_TOT - blockIdx.x * CHUNK_G);
    int nloc = 4 * ngrp;
    for (int j = tid; j < nloc; j += 256) {
        int b = lbk[j];
        int2 e = le[j];
        int t = (e.x >> 17) & 3;
        float v = __int_as_float(e.y);
        edata2[gbase[b] + (j - lbase[b])] =
            make_int2(e.x, (int)packbf(v * f0[t], v * f1[t]));
    }
}

// ---------------------------------------------------------------------------
// MFMA projection: Xp16[n][d] = pack(bf16(X[n]·Ws[0][:,d]), bf16(X[n]·Ws[1][:,d]))
// ---------------------------------------------------------------------------
#define AROW 136   // LDS row pitch in shorts (128 + 8 pad)
__global__ __launch_bounds__(256) void proj_mfma(const float* __restrict__ X,
                                                 const unsigned short* __restrict__ Wsb,
                                                 unsigned* __restrict__ Xp16) {
    __shared__ unsigned short a_lds[64 * AROW];   // 17408 B
    int tid  = threadIdx.x;
    int row0 = blockIdx.x * 64;

    const float4* X4 = (const float4*)X;
    #pragma unroll
    for (int i = 0; i < 8; ++i) {
        int gi = tid + 256 * i;          // float4 index within tile
        int r  = gi >> 5;
        int c4 = gi & 31;
        int row = row0 + r;
        float4 v = make_float4(0.f, 0.f, 0.f, 0.f);
        if (row < N_NODES) v = X4[(size_t)row * 32 + c4];
        *(uint2*)&a_lds[r * AROW + c4 * 4] = make_uint2(packbf(v.x, v.y),
                                                        packbf(v.z, v.w));
    }
    __syncthreads();

    int wave = tid >> 6, lane = tid & 63;
    int m = lane & 15, q = lane >> 4;

    short8x A[4];
    #pragma unroll
    for (int ks = 0; ks < 4; ++ks)
        A[ks] = *(const short8x*)&a_lds[(wave * 16 + m) * AROW + ks * 32 + q * 8];

    #pragma unroll
    for (int ct = 0; ct < 4; ++ct) {
        f32x4 acc0 = {0.f, 0.f, 0.f, 0.f};
        f32x4 acc1 = {0.f, 0.f, 0.f, 0.f};
        #pragma unroll
        for (int ks = 0; ks < 4; ++ks) {
            short8x B0 = *(const short8x*)(Wsb + (ct * 16 + m) * 128 + ks * 32 + q * 8);
            short8x B1 = *(const short8x*)(Wsb + 8192 + (ct * 16 + m) * 128 + ks * 32 + q * 8);
            acc0 = __builtin_amdgcn_mfma_f32_16x16x32_bf16(A[ks], B0, acc0, 0, 0, 0);
            acc1 = __builtin_amdgcn_mfma_f32_16x16x32_bf16(A[ks], B1, acc1, 0, 0, 0);
        }
        #pragma unroll
        for (int r = 0; r < 4; ++r) {
            int row = row0 + wave * 16 + q * 4 + r;
            if (row < N_NODES)
                Xp16[(size_t)row * DD + ct * 16 + m] = packbf(acc0[r], acc1[r]);
        }
    }
}

// ---------------------------------------------------------------------------
// Per-bucket in-LDS row-sort (128 rows/bucket) + per-row end offsets.
// 22 KB LDS, 256 threads, 782 blocks -> ~3 blocks/CU fill, 7 resident cap.
// ---------------------------------------------------------------------------
__global__ __launch_bounds__(256) void rowsort_kernel(const int* __restrict__ cursor,
                                                      int2* __restrict__ edata2,
                                                      int* __restrict__ offs) {
    __shared__ int rcnt[BROWS];
    __shared__ int rbase[BROWS];
    __shared__ int rcur[BROWS];
    __shared__ int2 le[BPAD];                     // 20480 B
    int b   = blockIdx.x;
    int tid = threadIdx.x;
    int bb  = b * BPAD;
    int cnt = cursor[b] - bb;
    if (tid < BROWS) rcnt[tid] = 0;
    __syncthreads();
    for (int j = tid; j < cnt; j += 256) {
        int2 e = edata2[bb + j];
        le[j] = e;
        atomicAdd(&rcnt[(e.x >> 19) & 127], 1);
    }
    __syncthreads();
    if (tid < 64) {                                // scan 128 row counts, 2/lane
        int c0 = rcnt[tid * 2], c1 = rcnt[tid * 2 + 1];
        int s = c0 + c1;
        int inc = s;
        #pragma unroll
        for (int off = 1; off < 64; off <<= 1) {
            int v = __shfl_up(inc, off);
            if (tid >= off) inc += v;
        }
        int base = inc - s;
        rbase[tid * 2]     = base;
        rbase[tid * 2 + 1] = base + c0;
    }
    __syncthreads();
    if (tid < BROWS) rcur[tid] = rbase[tid];
    __syncthreads();
    for (int j = tid; j < cnt; j += 256) {
        int2 e = le[j];
        int lr = (e.x >> 19) & 127;
        int pos = atomicAdd(&rcur[lr], 1);
        edata2[bb + pos] = e;
    }
    int row0  = b * BROWS;
    int nrows = min(BROWS, N_NODES - row0);
    if (tid < nrows)
        offs[row0 + tid] = bb + rbase[tid] + rcnt[tid];
}

// ---------------------------------------------------------------------------
// Quarter-wave bf16 gather: s16 = lane&15 covers d = {4s..4s+3} both channels
// as uint4 = 16 B/lane; sub = lane>>4 interleaves 4 edges per wave.
// ---------------------------------------------------------------------------
__device__ __forceinline__ void qfma(const uint4 h, unsigned wp,
                                     float4& a, float4& b) {
    float w0 = bflo(wp), w1 = bfhi(wp);
    a.x = fmaf(w0, bflo(h.x), a.x);
    a.y = fmaf(w1, bfhi(h.x), a.y);
    a.z = fmaf(w0, bflo(h.y), a.z);
    a.w = fmaf(w1, bfhi(h.y), a.w);
    b.x = fmaf(w0, bflo(h.z), b.x);
    b.y = fmaf(w1, bfhi(h.z), b.y);
    b.z = fmaf(w0, bflo(h.w), b.z);
    b.w = fmaf(w1, bfhi(h.w), b.w);
}

__device__ __forceinline__ void qreduce(float4& a, float4& b) {
    a.x += __shfl_xor(a.x, 16); a.y += __shfl_xor(a.y, 16);
    a.z += __shfl_xor(a.z, 16); a.w += __shfl_xor(a.w, 16);
    b.x += __shfl_xor(b.x, 16); b.y += __shfl_xor(b.y, 16);
    b.z += __shfl_xor(b.z, 16); b.w += __shfl_xor(b.w, 16);
    a.x += __shfl_xor(a.x, 32); a.y += __shfl_xor(a.y, 32);
    a.z += __shfl_xor(a.z, 32); a.w += __shfl_xor(a.w, 32);
    b.x += __shfl_xor(b.x, 32); b.y += __shfl_xor(b.y, 32);
    b.z += __shfl_xor(b.z, 32); b.w += __shfl_xor(b.w, 32);
}

__device__ __forceinline__ int row_beg(const int* offs, int row) {
    return ((row & 127) == 0) ? (row >> 7) * BPAD : offs[row - 1];
}

// Layer 1: all N rows; bf16 in (Xp16), bf16 out (H116).
__global__ __launch_bounds__(256) void spmm_gather(const unsigned* __restrict__ Hin16,
                                                   unsigned* __restrict__ Hout16,
                                                   const int* __restrict__ offs,
                                                   const int2* __restrict__ edata2) {
    int lane = threadIdx.x & 63;
    int s16 = lane & 15, sub = lane >> 4;
    int row  = (blockIdx.x * blockDim.x + threadIdx.x) >> 6;
    int beg = row_beg(offs, row);
    int end = offs[row];
    const uint4* hp = (const uint4*)Hin16;
    float4 a = make_float4(0.f, 0.f, 0.f, 0.f);
    float4 b = make_float4(0.f, 0.f, 0.f, 0.f);
    int i = beg + sub;
    for (; i + 4 < end; i += 8) {                 // 2 edges per quarter per iter
        int2 e0 = edata2[i];
        int2 e1 = edata2[i + 4];
        uint4 h0 = hp[(size_t)(e0.x & 0x1FFFF) * 16 + s16];
        uint4 h1 = hp[(size_t)(e1.x & 0x1FFFF) * 16 + s16];
        qfma(h0, (unsigned)e0.y, a, b);
        qfma(h1, (unsigned)e1.y, a, b);
    }
    if (i < end) {
        int2 e = edata2[i];
        uint4 h = hp[(size_t)(e.x & 0x1FFFF) * 16 + s16];
        qfma(h, (unsigned)e.y, a, b);
    }
    qreduce(a, b);
    if (sub == 0)
        ((uint4*)Hout16)[(size_t)row * 16 + s16] =
            make_uint4(packbf(a.x, a.y), packbf(a.z, a.w),
                       packbf(b.x, b.y), packbf(b.z, b.w));
}

// ---------------------------------------------------------------------------
// Fused layer-2 gather (target rows) + tail MLP. Block = 4 waves = 4 targets.
// Layer-2 edge weights = stored_l1_weight * (f_l2[t]/f_l1[t]).
// ---------------------------------------------------------------------------
__global__ __launch_bounds__(256) void tgt_tail_kernel(const unsigned* __restrict__ Hin16,
                                                       const unsigned* __restrict__ Xp16,
                                                       const int* __restrict__ offs,
                                                       const int2* __restrict__ edata2,
                                                       const float* __restrict__ cw,
                                                       const int* __restrict__ tgt,
                                                       const float* __restrict__ lin1_w,
                                                       const float* __restrict__ lin1_b,
                                                       const float* __restrict__ lin_w,
                                                       const float* __restrict__ lin_b,
                                                       float* __restrict__ out) {
    __shared__ float l1w[W_INF * DD];        // 32 KB
    __shared__ float lw[DD * NUM_CLASS];     // 4 KB
    __shared__ float l1b[DD];
    __shared__ float lb[NUM_CLASS];
    __shared__ float hc[4][W_INF];
    __shared__ float hmid[4][DD];

    int tid = threadIdx.x;
    {
        const float4* g = (const float4*)lin1_w;
        float4* s = (float4*)l1w;
        #pragma unroll
        for (int i = 0; i < 8; ++i) s[tid + 256 * i] = g[tid + 256 * i];
        ((float4*)lw)[tid] = ((const float4*)lin_w)[tid];
        if (tid < DD) l1b[tid] = lin1_b[tid];
        else if (tid < DD + NUM_CLASS) lb[tid - DD] = lin_b[tid - DD];
    }

    float f0a[T_TYPES], f1a[T_TYPES], f0b[T_TYPES], f1b[T_TYPES];
    load_filter(cw, 0, f0a, f1a);
    load_filter(cw, 1, f0b, f1b);
    float r0[T_TYPES], r1[T_TYPES];
    #pragma unroll
    for (int t = 0; t < T_TYPES; ++t) { r0[t] = f0b[t] / f0a[t]; r1[t] = f1b[t] / f1a[t]; }

    int w = tid >> 6, lane = tid & 63;
    int s16 = lane & 15, sub = lane >> 4;
    int m = blockIdx.x * 4 + w;               // M = 10000 = 2500*4
    int row = tgt[m];
    int beg = row_beg(offs, row);
    int end = offs[row];
    const uint4* hp = (const uint4*)Hin16;
    float4 a = make_float4(0.f, 0.f, 0.f, 0.f);
    float4 b = make_float4(0.f, 0.f, 0.f, 0.f);
    for (int i = beg + sub; i < end; i += 4) {
        int2 e = edata2[i];
        int t = (e.x >> 17) & 3;
        uint4 h = hp[(size_t)(e.x & 0x1FFFF) * 16 + s16];
        unsigned wp = (unsigned)e.y;
        float w0 = bflo(wp) * r0[t], w1 = bfhi(wp) * r1[t];
        a.x = fmaf(w0, bflo(h.x), a.x);
        a.y = fmaf(w1, bfhi(h.x), a.y);
        a.z = fmaf(w0, bflo(h.y), a.z);
        a.w = fmaf(w1, bfhi(h.y), a.w);
        b.x = fmaf(w0, bflo(h.z), b.x);
        b.y = fmaf(w1, bfhi(h.z), b.y);
        b.z = fmaf(w0, bflo(h.w), b.z);
        b.w = fmaf(w1, bfhi(h.w), b.w);
    }
    qreduce(a, b);

    if (sub == 0) {
        uint4 xu = ((const uint4*)Xp16)[(size_t)row * 16 + s16];
        int d0 = 4 * s16;
        hc[w][d0 + 0]      = fmaxf(BETA * bflo(xu.x) + (1.f - BETA) * a.x, 0.f);
        hc[w][DD + d0 + 0] = fmaxf(BETA * bfhi(xu.x) + (1.f - BETA) * a.y, 0.f);
        hc[w][d0 + 1]      = fmaxf(BETA * bflo(xu.y) + (1.f - BETA) * a.z, 0.f);
        hc[w][DD + d0 + 1] = fmaxf(BETA * bfhi(xu.y) + (1.f - BETA) * a.w, 0.f);
        hc[w][d0 + 2]      = fmaxf(BETA * bflo(xu.z) + (1.f - BETA) * b.x, 0.f);
        hc[w][DD + d0 + 2] = fmaxf(BETA * bfhi(xu.z) + (1.f - BETA) * b.y, 0.f);
        hc[w][d0 + 3]      = fmaxf(BETA * bflo(xu.w) + (1.f - BETA) * b.z, 0.f);
        hc[w][DD + d0 + 3] = fmaxf(BETA * bfhi(xu.w) + (1.f - BETA) * b.w, 0.f);
    }
    __syncthreads();

    float a1 = l1b[lane];
    #pragma unroll 8
    for (int k = 0; k < W_INF; ++k)
        a1 = fmaf(hc[w][k], l1w[k * DD + lane], a1);
    hmid[w][lane] = a1;
    __syncthreads();

    if (lane < NUM_CLASS) {
        float o = lb[lane];
        #pragma unroll 8
        for (int k = 0; k < DD; ++k)
            o = fmaf(hmid[w][k], lw[k * NUM_CLASS + lane], o);
        out[(size_t)m * NUM_CLASS + lane] = o;
    }
}

// ---------------------------------------------------------------------------
extern "C" void kernel_launch(void* const* d_in, const int* in_sizes, int n_in,
                              void* d_out, int out_size, void* d_ws, size_t ws_size,
                              hipStream_t stream) {
    const float* X            = (const float*)d_in[0];
    const float* edge_value   = (const float*)d_in[1];
    const float* conv_weights = (const float*)d_in[2];
    const float* Ws           = (const float*)d_in[3];
    const float* lin1_w       = (const float*)d_in[4];
    const float* lin1_b       = (const float*)d_in[5];
    const float* lin_w        = (const float*)d_in[6];
    const float* lin_b        = (const float*)d_in[7];
    const int*   edge_index   = (const int*)d_in[8];
    const int*   target_x     = (const int*)d_in[9];
    float* out = (float*)d_out;

    unsigned*       Xp16 = (unsigned*)d_ws;                   // 25.6 MB
    unsigned*       H116 = Xp16 + PLANE2;                     // 25.6 MB
    unsigned short* Wsb  = (unsigned short*)(H116 + PLANE2);  // 32 KB
    int*            offs = (int*)(Wsb + C_CH * W_INF * DD);   // N ints
    int*            cursor = offs + N_NODES;                  // 1024
    int2*           edata2 = (int2*)(cursor + 1024);          // NBKT*BPAD int2 (16.0 MB)

    prep_kernel<<<68, 256, 0, stream>>>(Ws, Wsb, cursor);
    partition_kernel<<<NPART_BLK, 256, 0, stream>>>(edge_index, edge_value,
                                                    conv_weights, cursor, edata2);
    proj_mfma<<<(N_NODES + 63) / 64, 256, 0, stream>>>(X, Wsb, Xp16);
    rowsort_kernel<<<NBKT, 256, 0, stream>>>(cursor, edata2, offs);
    spmm_gather<<<(N_NODES * 64) / 256, 256, 0, stream>>>(Xp16, H116, offs, edata2);
    tgt_tail_kernel<<<M_TGT / 4, 256, 0, stream>>>(H116, Xp16, offs, edata2,
                                                   conv_weights, target_x,
                                                   lin1_w, lin1_b, lin_w, lin_b, out);
}